// Round 12
// baseline (198.790 us; speedup 1.0000x reference)
//
#include <hip/hip_runtime.h>

#define N_NODES 100000
#define N_EDGES 1600000
#define BSH 9                      // 512 nodes per bucket
#define NB  196                    // ceil(N_NODES / 512)
#define EPB 4096                   // edges per bin block
#define CAPSH 14                   // 16384 binned slots per bucket (avg fill ~8163)
#define GB  ((N_EDGES + EPB - 1) / EPB)     // 391 bin blocks
#define GG  ((N_NODES + 127) / 128)         // 782 gemm blocks
#define NGRP 6250                  // node groups of 16 for agg kernels
#define AGRID (((NGRP + 3) / 4) * 8)        // 12504 blocks (octet -> 4 groups x 2 halves)

typedef short bf16x8 __attribute__((ext_vector_type(8)));
typedef float f32x4 __attribute__((ext_vector_type(4)));
typedef float f32x2 __attribute__((ext_vector_type(2)));

// ---------------- bf16 helpers (storage only; math in f32) ----------------

__device__ __forceinline__ unsigned pack_bf16x2(float a, float b) {
    unsigned ua = __float_as_uint(a), ub = __float_as_uint(b);
    unsigned ra = (ua + 0x7fffu + ((ua >> 16) & 1u)) >> 16;   // RNE
    unsigned rb = (ub + 0x7fffu + ((ub >> 16) & 1u)) >> 16;
    return ra | (rb << 16);
}
__device__ __forceinline__ unsigned short bf16_rne(float f) {
    unsigned u = __float_as_uint(f);
    return (unsigned short)((u + 0x7fffu + ((u >> 16) & 1u)) >> 16);
}
__device__ __forceinline__ f32x2 unpk(unsigned u) {
    f32x2 r;
    r.x = __uint_as_float(u << 16);
    r.y = __uint_as_float(u & 0xffff0000u);
    return r;
}

// ---- setup: W transforms + cursor init in one launch ----
// W[128][C] f32 -> Wt[C][128] bf16 with 16B-granule XOR swizzle:
// element (k,c) at Wt[c*128 + ((k>>3) ^ (c&7))*8 + (k&7)]

__device__ __forceinline__ void wt_body(const float* W, unsigned short* Wt, int C, int bid) {
    int t = bid * 256 + threadIdx.x;
    if (t >= 128 * C) return;
    int k = t / C, c = t % C;
    int g = k >> 3, j = k & 7;
    Wt[c * 128 + ((g ^ (c & 7)) << 3) + j] = bf16_rne(W[t]);
}

__global__ void setup_k(const float* __restrict__ W1, unsigned short* __restrict__ Wt1,
                        const float* __restrict__ W2, unsigned short* __restrict__ Wt2,
                        int* __restrict__ cursor) {
    int b = blockIdx.x;
    if (b < 64) { wt_body(W1, Wt1, 128, b); }
    else if (b < 96) { wt_body(W2, Wt2, 64, b - 64); }
    else {
        int t = threadIdx.x;
        if (t < NB) cursor[t] = t << CAPSH;
    }
}

// ---- fused: bin (blocks 0..GB-1)  ||  gemm1 (blocks GB..GB+GG-1) ----

__global__ __launch_bounds__(256) void bin_gemm1_k(
        const int* __restrict__ src, const int* __restrict__ dst,
        int* __restrict__ cursor, unsigned* __restrict__ binned,
        const float* __restrict__ X, const unsigned short* __restrict__ Wt,
        unsigned short* __restrict__ Y) {
    __shared__ int lhist[256];
    __shared__ int lcur[256];
    __shared__ short lds_w[128 * 128];   // 32 KB (gemm branch)
    int tid = threadIdx.x;

    if (blockIdx.x < GB) {
        lhist[tid] = 0;
        __syncthreads();
        int e0 = blockIdx.x * EPB;
#pragma unroll
        for (int i = 0; i < EPB / 256; ++i) {
            int e = e0 + i * 256 + tid;
            if (e < N_EDGES) atomicAdd(&lhist[dst[e] >> BSH], 1);
        }
        __syncthreads();
        {
            int c = lhist[tid];
            lcur[tid] = (tid < NB && c > 0) ? atomicAdd(&cursor[tid], c) : 0;
        }
        __syncthreads();
#pragma unroll
        for (int i = 0; i < EPB / 256; ++i) {
            int e = e0 + i * 256 + tid;
            if (e < N_EDGES) {
                int d = dst[e];
                int b = d >> BSH;
                int pos = atomicAdd(&lcur[b], 1);
                if (pos < ((b + 1) << CAPSH))   // capacity guard (never hits here)
                    binned[pos] = ((unsigned)(d & ((1 << BSH) - 1)) << 17) | (unsigned)src[e];
            }
        }
        return;
    }

    // gemm1: hw1[N,128](bf16) = X[N,128](f32) @ W1
    {
        const uint4* srcp = (const uint4*)Wt;
        uint4* dstp = (uint4*)lds_w;
        for (int i = tid; i < 128 * 16; i += 256) dstp[i] = srcp[i];
    }
    __syncthreads();
    int lane = tid & 63;
    int r16 = lane & 15, kq = lane >> 4;
    int rbase = (blockIdx.x - GB) * 128 + (tid >> 6) * 32;
    f32x4 acc[2][8] = {};
#pragma unroll
    for (int kk = 0; kk < 4; ++kk) {
        int k0 = kk * 32 + kq * 8;
        bf16x8 a[2];
#pragma unroll
        for (int rt = 0; rt < 2; ++rt) {
            int row = rbase + rt * 16 + r16;
            if (row < N_NODES) {
                const float* xp = X + (size_t)row * 128 + k0;
                float4 f0 = *(const float4*)xp;
                float4 f1 = *(const float4*)(xp + 4);
                uint4 uu = make_uint4(pack_bf16x2(f0.x, f0.y), pack_bf16x2(f0.z, f0.w),
                                      pack_bf16x2(f1.x, f1.y), pack_bf16x2(f1.z, f1.w));
                a[rt] = *(bf16x8*)&uu;
            } else {
                bf16x8 z = {0, 0, 0, 0, 0, 0, 0, 0};
                a[rt] = z;
            }
        }
#pragma unroll
        for (int c = 0; c < 8; ++c) {
            int col = c * 16 + r16;
            int gp = (kk * 4 + kq) ^ (col & 7);
            bf16x8 b = *(const bf16x8*)&lds_w[col * 128 + gp * 8];
            acc[0][c] = __builtin_amdgcn_mfma_f32_16x16x32_bf16(a[0], b, acc[0][c], 0, 0, 0);
            acc[1][c] = __builtin_amdgcn_mfma_f32_16x16x32_bf16(a[1], b, acc[1][c], 0, 0, 0);
        }
    }
#pragma unroll
    for (int rt = 0; rt < 2; ++rt) {
#pragma unroll
        for (int c = 0; c < 8; ++c) {
#pragma unroll
            for (int r = 0; r < 4; ++r) {
                int row = rbase + rt * 16 + kq * 4 + r;
                if (row < N_NODES)
                    Y[(size_t)row * 128 + c * 16 + r16] = bf16_rne(acc[rt][c][r]);
            }
        }
    }
}

// ---- degcsr: per bucket: count -> scan -> rowrange + dis -> place src-only edges ----

__global__ __launch_bounds__(256) void degcsr_k(const unsigned* __restrict__ binned,
                                                const int* __restrict__ cursor,
                                                int2* __restrict__ rowrange,
                                                float* __restrict__ dis,
                                                unsigned* __restrict__ edge, int n) {
    __shared__ int lcnt[1 << BSH];
    __shared__ int ls[256];
    int b = blockIdx.x, tid = threadIdx.x;
    for (int j = tid; j < (1 << BSH); j += 256) lcnt[j] = 0;
    __syncthreads();
    int base = b << CAPSH;
    int total = cursor[b] - base;
    for (int i = tid; i < total; i += 256)
        atomicAdd(&lcnt[binned[base + i] >> 17], 1);
    __syncthreads();
    int v0 = lcnt[2 * tid], v1 = lcnt[2 * tid + 1];
    int sv = v0 + v1;
    ls[tid] = sv;
    __syncthreads();
    for (int off = 1; off < 256; off <<= 1) {
        int t = 0;
        if (tid >= off) t = ls[tid - off];
        __syncthreads();
        ls[tid] += t;
        __syncthreads();
    }
    int pre = ls[tid] - sv;
    int start0 = base + pre;
    int start1 = start0 + v0;
    int nbase = b << BSH;
    int node0 = nbase + 2 * tid, node1 = node0 + 1;
    if (node0 < n) {
        rowrange[node0] = make_int2(start0, start0 + v0);
        dis[node0] = rsqrtf((float)(v0 + 1));
    }
    if (node1 < n) {
        rowrange[node1] = make_int2(start1, start1 + v1);
        dis[node1] = rsqrtf((float)(v1 + 1));
    }
    lcnt[2 * tid] = start0;       // reuse as fill cursors (owner-thread slots)
    lcnt[2 * tid + 1] = start1;
    __syncthreads();
    for (int i = tid; i < total; i += 256) {
        unsigned u = binned[base + i];
        int pos = atomicAdd(&lcnt[u >> 17], 1);
        edge[pos] = u & 0x1FFFFu;
    }
}

// ---- MFMA GEMM (layer 2): hw2[N,64](bf16) = h[N,128](bf16) @ W2 ----

__global__ __launch_bounds__(256) void gemm2_k(const unsigned short* __restrict__ Xv,
                                               const unsigned short* __restrict__ Wt,
                                               unsigned short* __restrict__ Y, int nrows) {
    __shared__ short lds_w[64 * 128];
    int tid = threadIdx.x;
    {
        const uint4* srcp = (const uint4*)Wt;
        uint4* dstp = (uint4*)lds_w;
        for (int i = tid; i < 64 * 16; i += 256) dstp[i] = srcp[i];
    }
    __syncthreads();
    int lane = tid & 63;
    int r16 = lane & 15, kq = lane >> 4;
    int rbase = blockIdx.x * 128 + (tid >> 6) * 32;
    f32x4 acc[2][4] = {};
#pragma unroll
    for (int kk = 0; kk < 4; ++kk) {
        int k0 = kk * 32 + kq * 8;
        bf16x8 a[2];
#pragma unroll
        for (int rt = 0; rt < 2; ++rt) {
            int row = rbase + rt * 16 + r16;
            if (row < nrows) {
                a[rt] = *(const bf16x8*)(Xv + (size_t)row * 128 + k0);
            } else {
                bf16x8 z = {0, 0, 0, 0, 0, 0, 0, 0};
                a[rt] = z;
            }
        }
#pragma unroll
        for (int c = 0; c < 4; ++c) {
            int col = c * 16 + r16;
            int gp = (kk * 4 + kq) ^ (col & 7);
            bf16x8 b = *(const bf16x8*)&lds_w[col * 128 + gp * 8];
            acc[0][c] = __builtin_amdgcn_mfma_f32_16x16x32_bf16(a[0], b, acc[0][c], 0, 0, 0);
            acc[1][c] = __builtin_amdgcn_mfma_f32_16x16x32_bf16(a[1], b, acc[1][c], 0, 0, 0);
        }
    }
#pragma unroll
    for (int rt = 0; rt < 2; ++rt) {
#pragma unroll
        for (int c = 0; c < 4; ++c) {
#pragma unroll
            for (int r = 0; r < 4; ++r) {
                int row = rbase + rt * 16 + kq * 4 + r;
                if (row < nrows)
                    Y[(size_t)row * 64 + c * 16 + r16] = bf16_rne(acc[rt][c][r]);
            }
        }
    }
}

// ---------------- Aggregation: XCD-feature-split ----------------
// Block octet slot (blockIdx & 7) keys the feature half: slots 0-3 -> cols [0,H/2),
// slots 4-7 -> cols [H/2,H). With round-robin block->XCD dispatch, each XCD's L2
// only holds half the feature matrix -> ~2x reuse per L2. Each 16-lane group owns
// one node's half-row; edge record = src only; dis_d folded at the end.

// Layer 1: half-row = 64 bf16 = 128 B = 16 lanes x uint2. Output h (bf16).
__global__ void agg1_k(const unsigned* __restrict__ hw, const int2* __restrict__ rowrange,
                       const unsigned* __restrict__ edge, const float* __restrict__ dis,
                       const float* __restrict__ bias, const float* __restrict__ aslope,
                       unsigned* __restrict__ out, int n) {
    int b = blockIdx.x;
    unsigned half = (b & 7) >> 2;
    int ng = (b >> 3) * 4 + (b & 3);
    if (ng >= NGRP) return;
    int tid = threadIdx.x;
    int lane = tid & 63;
    int g = lane >> 4;
    unsigned li = lane & 15;
    int node = ng * 16 + (tid >> 6) * 4 + g;
    bool valid = node < n;
    int2 rr = valid ? rowrange[node] : make_int2(0, 0);
    int e0 = rr.x, e1 = rr.y;
    unsigned rowoff = (half << 7) | (li << 3);
    const char* hwb = (const char*)hw;
    f32x2 acc[2] = {};
    int e = e0;
    while (__any(e < e1)) {
        if (e < e1) {
            unsigned s[8];
            uint2 v[8];
            float wgt[8];
#pragma unroll
            for (int u = 0; u < 8; ++u) {
                int ee = e + u;
                unsigned ec = (unsigned)((ee < e1) ? ee : (e1 - 1));
                s[u] = edge[ec];
            }
#pragma unroll
            for (int u = 0; u < 8; ++u) {
                v[u] = *(const uint2*)(hwb + ((s[u] << 8) | rowoff));
                wgt[u] = dis[s[u]];
            }
#pragma unroll
            for (int u = 0; u < 8; ++u) {
                float nr = (e + u < e1) ? wgt[u] : 0.f;
                f32x2 nr2 = {nr, nr};
                acc[0] += unpk(v[u].x) * nr2;
                acc[1] += unpk(v[u].y) * nr2;
            }
        }
        e += 8;
    }
    if (valid) {
        float dn = dis[node];
        f32x2 dn2 = {dn, dn};
        uint2 v = *(const uint2*)(hwb + (((unsigned)node << 8) | rowoff));
        acc[0] += unpk(v.x) * dn2;
        acc[1] += unpk(v.y) * dn2;
        float4 bb = ((const float4*)bias)[half * 16 + li];
        float al = aslope[0];
        float r[4] = {dn * acc[0].x + bb.x, dn * acc[0].y + bb.y,
                      dn * acc[1].x + bb.z, dn * acc[1].y + bb.w};
#pragma unroll
        for (int j = 0; j < 4; ++j) r[j] = (r[j] >= 0.f) ? r[j] : al * r[j];
        uint2 o = make_uint2(pack_bf16x2(r[0], r[1]), pack_bf16x2(r[2], r[3]));
        *(uint2*)(out + (size_t)node * 64 + half * 32 + li * 2) = o;
    }
}

// Layer 2: half-row = 32 bf16 = 64 B = 16 lanes x uint. Output f32.
__global__ void agg2_k(const unsigned* __restrict__ hw, const int2* __restrict__ rowrange,
                       const unsigned* __restrict__ edge, const float* __restrict__ dis,
                       const float* __restrict__ bias, const float* __restrict__ aslope,
                       float* __restrict__ out, int n) {
    int b = blockIdx.x;
    unsigned half = (b & 7) >> 2;
    int ng = (b >> 3) * 4 + (b & 3);
    if (ng >= NGRP) return;
    int tid = threadIdx.x;
    int lane = tid & 63;
    int g = lane >> 4;
    unsigned li = lane & 15;
    int node = ng * 16 + (tid >> 6) * 4 + g;
    bool valid = node < n;
    int2 rr = valid ? rowrange[node] : make_int2(0, 0);
    int e0 = rr.x, e1 = rr.y;
    unsigned rowoff = (half << 6) | (li << 2);
    const char* hwb = (const char*)hw;
    f32x2 acc = {};
    int e = e0;
    while (__any(e < e1)) {
        if (e < e1) {
            unsigned s[8];
            unsigned v[8];
            float wgt[8];
#pragma unroll
            for (int u = 0; u < 8; ++u) {
                int ee = e + u;
                unsigned ec = (unsigned)((ee < e1) ? ee : (e1 - 1));
                s[u] = edge[ec];
            }
#pragma unroll
            for (int u = 0; u < 8; ++u) {
                v[u] = *(const unsigned*)(hwb + ((s[u] << 7) | rowoff));
                wgt[u] = dis[s[u]];
            }
#pragma unroll
            for (int u = 0; u < 8; ++u) {
                float nr = (e + u < e1) ? wgt[u] : 0.f;
                f32x2 nr2 = {nr, nr};
                acc += unpk(v[u]) * nr2;
            }
        }
        e += 8;
    }
    if (valid) {
        float dn = dis[node];
        f32x2 dn2 = {dn, dn};
        unsigned v = *(const unsigned*)(hwb + (((unsigned)node << 7) | rowoff));
        acc += unpk(v) * dn2;
        float2 bb = ((const float2*)bias)[half * 16 + li];
        float al = aslope[0];
        float r[2] = {dn * acc.x + bb.x, dn * acc.y + bb.y};
#pragma unroll
        for (int j = 0; j < 2; ++j) r[j] = (r[j] >= 0.f) ? r[j] : al * r[j];
        *(float2*)(out + (size_t)node * 64 + half * 32 + li * 2) = make_float2(r[0], r[1]);
    }
}

// ---------------- launch ----------------

extern "C" void kernel_launch(void* const* d_in, const int* in_sizes, int n_in,
                              void* d_out, int out_size, void* d_ws, size_t ws_size,
                              hipStream_t stream) {
    const float* x  = (const float*)d_in[0];
    const int*   ei = (const int*)d_in[1];
    const int*   src = ei;
    const int*   dst = ei + N_EDGES;
    const float* W1 = (const float*)d_in[2];
    const float* b1 = (const float*)d_in[3];
    const float* W2 = (const float*)d_in[4];
    const float* b2 = (const float*)d_in[5];
    const float* a  = (const float*)d_in[6];
    float* out = (float*)d_out;

    char* ws = (char*)d_ws;
    size_t off = 0;
    auto alloc = [&](size_t bytes) -> void* {
        void* p = ws + off;
        off += (bytes + 255) & ~(size_t)255;
        return p;
    };
    int2*           rowrange  = (int2*)alloc((size_t)N_NODES * 8);
    float*          dis       = (float*)alloc((size_t)N_NODES * 4);
    int*            cursor    = (int*)alloc(NB * 4);
    unsigned*       binned    = (unsigned*)alloc((size_t)NB * (1 << CAPSH) * 4);  // 12.8 MB
    unsigned*       edge      = (unsigned*)alloc((size_t)NB * (1 << CAPSH) * 4);  // 12.8 MB
    unsigned*       hw1       = (unsigned*)alloc((size_t)N_NODES * 64 * 4);  // bf16 [N,128]
    unsigned*       hbuf      = (unsigned*)alloc((size_t)N_NODES * 64 * 4);  // bf16 [N,128]
    unsigned*       hw2       = (unsigned*)alloc((size_t)N_NODES * 32 * 4);  // bf16 [N,64]
    unsigned short* Wt1       = (unsigned short*)alloc(128 * 128 * 2);
    unsigned short* Wt2       = (unsigned short*)alloc(64 * 128 * 2);

    setup_k<<<97, 256, 0, stream>>>(W1, Wt1, W2, Wt2, cursor);
    bin_gemm1_k<<<GB + GG, 256, 0, stream>>>(src, dst, cursor, binned,
                                             x, Wt1, (unsigned short*)hw1);
    degcsr_k<<<NB, 256, 0, stream>>>(binned, cursor, rowrange, dis, edge, N_NODES);

    agg1_k<<<AGRID, 256, 0, stream>>>(hw1, rowrange, edge, dis, b1, a, hbuf, N_NODES);
    gemm2_k<<<GG, 256, 0, stream>>>((unsigned short*)hbuf, Wt2, (unsigned short*)hw2, N_NODES);
    agg2_k<<<AGRID, 256, 0, stream>>>(hw2, rowrange, edge, dis, b2, a, out, N_NODES);
}

// Round 13
// 167.482 us; speedup vs baseline: 1.1869x; 1.1869x over previous
//
#include <hip/hip_runtime.h>

#define N_NODES 100000
#define N_EDGES 1600000
#define BSH 9                      // 512 nodes per bucket
#define NB  196                    // ceil(N_NODES / 512)
#define EPB 4096                   // edges per bin block
#define CAPSH 14                   // 16384 binned slots per bucket (avg fill ~8163)
#define GB  ((N_EDGES + EPB - 1) / EPB)     // 391 bin blocks
#define GG  ((N_NODES + 127) / 128)         // 782 gemm blocks

typedef short bf16x8 __attribute__((ext_vector_type(8)));
typedef float f32x4 __attribute__((ext_vector_type(4)));
typedef float f32x2 __attribute__((ext_vector_type(2)));

// ---------------- bf16 helpers (storage only; math in f32) ----------------

__device__ __forceinline__ unsigned pack_bf16x2(float a, float b) {
    unsigned ua = __float_as_uint(a), ub = __float_as_uint(b);
    unsigned ra = (ua + 0x7fffu + ((ua >> 16) & 1u)) >> 16;   // RNE
    unsigned rb = (ub + 0x7fffu + ((ub >> 16) & 1u)) >> 16;
    return ra | (rb << 16);
}
__device__ __forceinline__ unsigned short bf16_rne(float f) {
    unsigned u = __float_as_uint(f);
    return (unsigned short)((u + 0x7fffu + ((u >> 16) & 1u)) >> 16);
}
__device__ __forceinline__ f32x2 unpk(unsigned u) {
    f32x2 r;
    r.x = __uint_as_float(u << 16);
    r.y = __uint_as_float(u & 0xffff0000u);
    return r;
}

// W[128][C] f32 -> Wt[C][128] bf16 with 16B-granule XOR swizzle:
// element (k,c) at Wt[c*128 + ((k>>3) ^ (c&7))*8 + (k&7)]
__device__ __forceinline__ void wt_body(const float* W, unsigned short* Wt, int C, int bid) {
    int t = bid * 256 + threadIdx.x;
    if (t >= 128 * C) return;
    int k = t / C, c = t % C;
    int g = k >> 3, j = k & 7;
    Wt[c * 128 + ((g ^ (c & 7)) << 3) + j] = bf16_rne(W[t]);
}

// ---- kernel A: bin (blocks 0..GB-1)  ||  wt transforms (blocks GB..GB+95) ----
// cursor is ZERO-initialized (memset); bucket base (b<<CAPSH) added in-kernel.

__global__ __launch_bounds__(256) void bin_wt_k(
        const int* __restrict__ src, const int* __restrict__ dst,
        int* __restrict__ cursor, unsigned* __restrict__ binned,
        const float* __restrict__ W1, unsigned short* __restrict__ Wt1,
        const float* __restrict__ W2, unsigned short* __restrict__ Wt2) {
    int tid = threadIdx.x;
    if (blockIdx.x >= GB) {
        int b2 = blockIdx.x - GB;
        if (b2 < 64) wt_body(W1, Wt1, 128, b2);
        else wt_body(W2, Wt2, 64, b2 - 64);
        return;
    }
    __shared__ int lhist[256];
    __shared__ int lcur[256];
    lhist[tid] = 0;
    __syncthreads();
    int e0 = blockIdx.x * EPB;
#pragma unroll
    for (int i = 0; i < EPB / 256; ++i) {
        int e = e0 + i * 256 + tid;
        if (e < N_EDGES) atomicAdd(&lhist[dst[e] >> BSH], 1);
    }
    __syncthreads();
    {
        int c = lhist[tid];
        lcur[tid] = (tid < NB && c > 0) ? ((tid << CAPSH) + atomicAdd(&cursor[tid], c)) : 0;
    }
    __syncthreads();
#pragma unroll
    for (int i = 0; i < EPB / 256; ++i) {
        int e = e0 + i * 256 + tid;
        if (e < N_EDGES) {
            int d = dst[e];
            int b = d >> BSH;
            int pos = atomicAdd(&lcur[b], 1);
            if (pos < ((b + 1) << CAPSH))   // capacity guard (never hits here)
                binned[pos] = ((unsigned)(d & ((1 << BSH) - 1)) << 17) | (unsigned)src[e];
        }
    }
}

// ---- kernel B: degcsr (blocks 0..NB-1)  ||  gemm1 (blocks NB..NB+GG-1) ----
// degcsr: per bucket count -> scan -> rowrange + dis -> place src-only edges.
// gemm1: hw1[N,128](bf16) = X[N,128](f32) @ W1 (MFMA).

__global__ __launch_bounds__(256) void degcsr_gemm1_k(
        const unsigned* __restrict__ binned, const int* __restrict__ cursor,
        int2* __restrict__ rowrange, float* __restrict__ dis,
        unsigned* __restrict__ edge,
        const float* __restrict__ X, const unsigned short* __restrict__ Wt,
        unsigned short* __restrict__ Y, int n) {
    __shared__ char smem[128 * 128 * 2];   // 32 KB, overlaid per branch
    int tid = threadIdx.x;

    if (blockIdx.x < NB) {
        int* lcnt = (int*)smem;                       // [512]
        int* ls   = (int*)(smem + (1 << BSH) * 4);    // [256]
        int b = blockIdx.x;
        for (int j = tid; j < (1 << BSH); j += 256) lcnt[j] = 0;
        __syncthreads();
        int base = b << CAPSH;
        int total = cursor[b];
        for (int i = tid; i < total; i += 256)
            atomicAdd(&lcnt[binned[base + i] >> 17], 1);
        __syncthreads();
        int v0 = lcnt[2 * tid], v1 = lcnt[2 * tid + 1];
        int sv = v0 + v1;
        ls[tid] = sv;
        __syncthreads();
        for (int off = 1; off < 256; off <<= 1) {
            int t = 0;
            if (tid >= off) t = ls[tid - off];
            __syncthreads();
            ls[tid] += t;
            __syncthreads();
        }
        int pre = ls[tid] - sv;
        int start0 = base + pre;
        int start1 = start0 + v0;
        int nbase = b << BSH;
        int node0 = nbase + 2 * tid, node1 = node0 + 1;
        if (node0 < n) {
            rowrange[node0] = make_int2(start0, start0 + v0);
            dis[node0] = rsqrtf((float)(v0 + 1));
        }
        if (node1 < n) {
            rowrange[node1] = make_int2(start1, start1 + v1);
            dis[node1] = rsqrtf((float)(v1 + 1));
        }
        lcnt[2 * tid] = start0;       // reuse as fill cursors (owner-thread slots)
        lcnt[2 * tid + 1] = start1;
        __syncthreads();
        for (int i = tid; i < total; i += 256) {
            unsigned u = binned[base + i];
            int pos = atomicAdd(&lcnt[u >> 17], 1);
            edge[pos] = u & 0x1FFFFu;
        }
        return;
    }

    // gemm1
    short* lds_w = (short*)smem;
    {
        const uint4* srcp = (const uint4*)Wt;
        uint4* dstp = (uint4*)lds_w;
        for (int i = tid; i < 128 * 16; i += 256) dstp[i] = srcp[i];
    }
    __syncthreads();
    int lane = tid & 63;
    int r16 = lane & 15, kq = lane >> 4;
    int rbase = (blockIdx.x - NB) * 128 + (tid >> 6) * 32;
    f32x4 acc[2][8] = {};
#pragma unroll
    for (int kk = 0; kk < 4; ++kk) {
        int k0 = kk * 32 + kq * 8;
        bf16x8 a[2];
#pragma unroll
        for (int rt = 0; rt < 2; ++rt) {
            int row = rbase + rt * 16 + r16;
            if (row < N_NODES) {
                const float* xp = X + (size_t)row * 128 + k0;
                float4 f0 = *(const float4*)xp;
                float4 f1 = *(const float4*)(xp + 4);
                uint4 uu = make_uint4(pack_bf16x2(f0.x, f0.y), pack_bf16x2(f0.z, f0.w),
                                      pack_bf16x2(f1.x, f1.y), pack_bf16x2(f1.z, f1.w));
                a[rt] = *(bf16x8*)&uu;
            } else {
                bf16x8 z = {0, 0, 0, 0, 0, 0, 0, 0};
                a[rt] = z;
            }
        }
#pragma unroll
        for (int c = 0; c < 8; ++c) {
            int col = c * 16 + r16;
            int gp = (kk * 4 + kq) ^ (col & 7);
            bf16x8 b = *(const bf16x8*)&lds_w[col * 128 + gp * 8];
            acc[0][c] = __builtin_amdgcn_mfma_f32_16x16x32_bf16(a[0], b, acc[0][c], 0, 0, 0);
            acc[1][c] = __builtin_amdgcn_mfma_f32_16x16x32_bf16(a[1], b, acc[1][c], 0, 0, 0);
        }
    }
#pragma unroll
    for (int rt = 0; rt < 2; ++rt) {
#pragma unroll
        for (int c = 0; c < 8; ++c) {
#pragma unroll
            for (int r = 0; r < 4; ++r) {
                int row = rbase + rt * 16 + kq * 4 + r;
                if (row < N_NODES)
                    Y[(size_t)row * 128 + c * 16 + r16] = bf16_rne(acc[rt][c][r]);
            }
        }
    }
}

// ---- MFMA GEMM (layer 2): hw2[N,64](bf16) = h[N,128](bf16) @ W2 ----

__global__ __launch_bounds__(256) void gemm2_k(const unsigned short* __restrict__ Xv,
                                               const unsigned short* __restrict__ Wt,
                                               unsigned short* __restrict__ Y, int nrows) {
    __shared__ short lds_w[64 * 128];
    int tid = threadIdx.x;
    {
        const uint4* srcp = (const uint4*)Wt;
        uint4* dstp = (uint4*)lds_w;
        for (int i = tid; i < 64 * 16; i += 256) dstp[i] = srcp[i];
    }
    __syncthreads();
    int lane = tid & 63;
    int r16 = lane & 15, kq = lane >> 4;
    int rbase = blockIdx.x * 128 + (tid >> 6) * 32;
    f32x4 acc[2][4] = {};
#pragma unroll
    for (int kk = 0; kk < 4; ++kk) {
        int k0 = kk * 32 + kq * 8;
        bf16x8 a[2];
#pragma unroll
        for (int rt = 0; rt < 2; ++rt) {
            int row = rbase + rt * 16 + r16;
            if (row < nrows) {
                a[rt] = *(const bf16x8*)(Xv + (size_t)row * 128 + k0);
            } else {
                bf16x8 z = {0, 0, 0, 0, 0, 0, 0, 0};
                a[rt] = z;
            }
        }
#pragma unroll
        for (int c = 0; c < 4; ++c) {
            int col = c * 16 + r16;
            int gp = (kk * 4 + kq) ^ (col & 7);
            bf16x8 b = *(const bf16x8*)&lds_w[col * 128 + gp * 8];
            acc[0][c] = __builtin_amdgcn_mfma_f32_16x16x32_bf16(a[0], b, acc[0][c], 0, 0, 0);
            acc[1][c] = __builtin_amdgcn_mfma_f32_16x16x32_bf16(a[1], b, acc[1][c], 0, 0, 0);
        }
    }
#pragma unroll
    for (int rt = 0; rt < 2; ++rt) {
#pragma unroll
        for (int c = 0; c < 4; ++c) {
#pragma unroll
            for (int r = 0; r < 4; ++r) {
                int row = rbase + rt * 16 + kq * 4 + r;
                if (row < nrows)
                    Y[(size_t)row * 64 + c * 16 + r16] = bf16_rne(acc[rt][c][r]);
            }
        }
    }
}

// ---------------- Aggregation (R11 structure) ----------------
// Edge record = src only; weight dis[src] gathered (L2-hot table);
// dis_d folded at the end: out = dis_d*(sum + dis_d*hw_d) + bias, PReLU.

// Layer 1: 16-lane group per node, full 256B row (uint4/lane), 4 edges in flight.
__global__ void agg1_k(const unsigned* __restrict__ hw, const int2* __restrict__ rowrange,
                       const unsigned* __restrict__ edge, const float* __restrict__ dis,
                       const float* __restrict__ bias, const float* __restrict__ aslope,
                       unsigned* __restrict__ out, int n) {
    int w = (blockIdx.x * 256 + threadIdx.x) >> 6;
    int lane = threadIdx.x & 63;
    int g = lane >> 4;
    unsigned li = lane & 15;
    int node = w * 4 + g;
    bool valid = node < n;
    int2 rr = valid ? rowrange[node] : make_int2(0, 0);
    int e0 = rr.x, e1 = rr.y;
    unsigned rowoff = li << 4;
    const char* hwb = (const char*)hw;
    f32x2 acc[4] = {};
    int e = e0;
    while (__any(e < e1)) {
        if (e < e1) {
            unsigned s[4];
            uint4 v[4];
            float wgt[4];
#pragma unroll
            for (int u = 0; u < 4; ++u) {
                int ee = e + u;
                unsigned ec = (unsigned)((ee < e1) ? ee : (e1 - 1));
                s[u] = edge[ec];
            }
#pragma unroll
            for (int u = 0; u < 4; ++u) {
                v[u] = *(const uint4*)(hwb + ((s[u] << 8) | rowoff));
                wgt[u] = dis[s[u]];
            }
#pragma unroll
            for (int u = 0; u < 4; ++u) {
                float nr = (e + u < e1) ? wgt[u] : 0.f;
                f32x2 nr2 = {nr, nr};
                acc[0] += unpk(v[u].x) * nr2;
                acc[1] += unpk(v[u].y) * nr2;
                acc[2] += unpk(v[u].z) * nr2;
                acc[3] += unpk(v[u].w) * nr2;
            }
        }
        e += 4;
    }
    if (valid) {
        float dn = dis[node];
        f32x2 dn2 = {dn, dn};
        uint4 v = *(const uint4*)(hwb + (((unsigned)node << 8) | rowoff));
        acc[0] += unpk(v.x) * dn2;
        acc[1] += unpk(v.y) * dn2;
        acc[2] += unpk(v.z) * dn2;
        acc[3] += unpk(v.w) * dn2;
        float4 b0 = ((const float4*)bias)[li * 2];
        float4 b1 = ((const float4*)bias)[li * 2 + 1];
        float al = aslope[0];
        float r[8] = {dn * acc[0].x + b0.x, dn * acc[0].y + b0.y,
                      dn * acc[1].x + b0.z, dn * acc[1].y + b0.w,
                      dn * acc[2].x + b1.x, dn * acc[2].y + b1.y,
                      dn * acc[3].x + b1.z, dn * acc[3].y + b1.w};
#pragma unroll
        for (int j = 0; j < 8; ++j) r[j] = (r[j] >= 0.f) ? r[j] : al * r[j];
        uint4 o = make_uint4(pack_bf16x2(r[0], r[1]), pack_bf16x2(r[2], r[3]),
                             pack_bf16x2(r[4], r[5]), pack_bf16x2(r[6], r[7]));
        *(uint4*)(out + (size_t)node * 64 + li * 4) = o;
    }
}

// Layer 2: 8-lane group per node (8 nodes/wave), full 128B row (uint4/lane),
// 4 edges in flight. Output f32 (two float4 per lane).
__global__ void agg2_k(const unsigned* __restrict__ hw, const int2* __restrict__ rowrange,
                       const unsigned* __restrict__ edge, const float* __restrict__ dis,
                       const float* __restrict__ bias, const float* __restrict__ aslope,
                       float* __restrict__ out, int n) {
    int w = (blockIdx.x * 256 + threadIdx.x) >> 6;
    int lane = threadIdx.x & 63;
    int g = lane >> 3;                 // node slot 0..7
    unsigned li = lane & 7;            // 16B granule within 128B row
    int node = w * 8 + g;
    bool valid = node < n;
    int2 rr = valid ? rowrange[node] : make_int2(0, 0);
    int e0 = rr.x, e1 = rr.y;
    unsigned rowoff = li << 4;
    const char* hwb = (const char*)hw;
    f32x2 acc[4] = {};
    int e = e0;
    while (__any(e < e1)) {
        if (e < e1) {
            unsigned s[4];
            uint4 v[4];
            float wgt[4];
#pragma unroll
            for (int u = 0; u < 4; ++u) {
                int ee = e + u;
                unsigned ec = (unsigned)((ee < e1) ? ee : (e1 - 1));
                s[u] = edge[ec];
            }
#pragma unroll
            for (int u = 0; u < 4; ++u) {
                v[u] = *(const uint4*)(hwb + ((s[u] << 7) | rowoff));
                wgt[u] = dis[s[u]];
            }
#pragma unroll
            for (int u = 0; u < 4; ++u) {
                float nr = (e + u < e1) ? wgt[u] : 0.f;
                f32x2 nr2 = {nr, nr};
                acc[0] += unpk(v[u].x) * nr2;
                acc[1] += unpk(v[u].y) * nr2;
                acc[2] += unpk(v[u].z) * nr2;
                acc[3] += unpk(v[u].w) * nr2;
            }
        }
        e += 4;
    }
    if (valid) {
        float dn = dis[node];
        f32x2 dn2 = {dn, dn};
        uint4 v = *(const uint4*)(hwb + (((unsigned)node << 7) | rowoff));
        acc[0] += unpk(v.x) * dn2;
        acc[1] += unpk(v.y) * dn2;
        acc[2] += unpk(v.z) * dn2;
        acc[3] += unpk(v.w) * dn2;
        float4 b0 = ((const float4*)bias)[li * 2];
        float4 b1 = ((const float4*)bias)[li * 2 + 1];
        float al = aslope[0];
        float r[8] = {dn * acc[0].x + b0.x, dn * acc[0].y + b0.y,
                      dn * acc[1].x + b0.z, dn * acc[1].y + b0.w,
                      dn * acc[2].x + b1.x, dn * acc[2].y + b1.y,
                      dn * acc[3].x + b1.z, dn * acc[3].y + b1.w};
#pragma unroll
        for (int j = 0; j < 8; ++j) r[j] = (r[j] >= 0.f) ? r[j] : al * r[j];
        float* op = out + (size_t)node * 64 + li * 8;
        *(float4*)op = make_float4(r[0], r[1], r[2], r[3]);
        *(float4*)(op + 4) = make_float4(r[4], r[5], r[6], r[7]);
    }
}

// ---------------- launch ----------------

extern "C" void kernel_launch(void* const* d_in, const int* in_sizes, int n_in,
                              void* d_out, int out_size, void* d_ws, size_t ws_size,
                              hipStream_t stream) {
    const float* x  = (const float*)d_in[0];
    const int*   ei = (const int*)d_in[1];
    const int*   src = ei;
    const int*   dst = ei + N_EDGES;
    const float* W1 = (const float*)d_in[2];
    const float* b1 = (const float*)d_in[3];
    const float* W2 = (const float*)d_in[4];
    const float* b2 = (const float*)d_in[5];
    const float* a  = (const float*)d_in[6];
    float* out = (float*)d_out;

    char* ws = (char*)d_ws;
    size_t off = 0;
    auto alloc = [&](size_t bytes) -> void* {
        void* p = ws + off;
        off += (bytes + 255) & ~(size_t)255;
        return p;
    };
    int2*           rowrange  = (int2*)alloc((size_t)N_NODES * 8);
    float*          dis       = (float*)alloc((size_t)N_NODES * 4);
    int*            cursor    = (int*)alloc(NB * 4);
    unsigned*       binned    = (unsigned*)alloc((size_t)NB * (1 << CAPSH) * 4);  // 12.8 MB
    unsigned*       edge      = (unsigned*)alloc((size_t)NB * (1 << CAPSH) * 4);  // 12.8 MB
    unsigned*       hw1       = (unsigned*)alloc((size_t)N_NODES * 64 * 4);  // bf16 [N,128]
    unsigned*       hbuf      = (unsigned*)alloc((size_t)N_NODES * 64 * 4);  // bf16 [N,128]
    unsigned*       hw2       = (unsigned*)alloc((size_t)N_NODES * 32 * 4);  // bf16 [N,64]
    unsigned short* Wt1       = (unsigned short*)alloc(128 * 128 * 2);
    unsigned short* Wt2       = (unsigned short*)alloc(64 * 128 * 2);

    hipMemsetAsync(cursor, 0, NB * 4, stream);

    bin_wt_k<<<GB + 96, 256, 0, stream>>>(src, dst, cursor, binned, W1, Wt1, W2, Wt2);
    degcsr_gemm1_k<<<NB + GG, 256, 0, stream>>>(binned, cursor, rowrange, dis, edge,
                                                x, Wt1, (unsigned short*)hw1, N_NODES);
    agg1_k<<<6250, 256, 0, stream>>>(hw1, rowrange, edge, dis, b1, a, hbuf, N_NODES);
    gemm2_k<<<GG, 256, 0, stream>>>((unsigned short*)hbuf, Wt2, (unsigned short*)hw2, N_NODES);
    agg2_k<<<3125, 256, 0, stream>>>(hw2, rowrange, edge, dis, b2, a, out, N_NODES);
}